// Round 1
// baseline (2091.029 us; speedup 1.0000x reference)
//
#include <hip/hip_runtime.h>
#include <math.h>

#define H 768
#define S 1024
#define BATCH 2
#define T 2048  // BATCH*S

// ======================= small kernels =======================

// ybar[b,c] = mean_s y[b,s,c]   (grid 6 x 256 = 1536 threads)
__global__ __launch_bounds__(256) void meany_k(const float* __restrict__ Y, float* __restrict__ ybar) {
  int t = blockIdx.x * 256 + threadIdx.x;
  int b = t / H, c = t % H;
  const float* yp = Y + (size_t)b * S * H + c;
  float s = 0.f;
  for (int j = 0; j < S; ++j) s += yp[(size_t)j * H];
  ybar[t] = s * (1.0f / (float)S);
}

// O[b,n] = act( sum_k A[b,k] * W[k*H + n] + bias[n] )  for 2x768 outputs
__global__ __launch_bounds__(256) void gemv_k(const float* __restrict__ A, const float* __restrict__ W,
                                              const float* __restrict__ bias, float* __restrict__ O, int act) {
  int t = blockIdx.x * 256 + threadIdx.x;
  int b = t / H, n = t % H;
  const float* a = A + b * H;
  float s = bias ? bias[n] : 0.f;
  for (int k = 0; k < H; ++k) s = fmaf(a[k], W[(size_t)k * H + n], s);
  if (act) s = tanhf(s);
  O[t] = s;
}

// ======================= tiled fp32 GEMM =======================
// C(T x H) = act( A1(T x K)@W1 + [A2(T x K)@W2] + bias[col] + perbatch[b,col] )
#define BM 64
#define BN 64
#define BK 16

__global__ __launch_bounds__(256) void gemm_k(
    const float* __restrict__ A1, const float* __restrict__ W1,
    const float* __restrict__ A2, const float* __restrict__ W2,
    const float* __restrict__ bias, const float* __restrict__ perbatch,
    float* __restrict__ C, int K, int act)
{
  __shared__ float sA[BM][BK + 1];
  __shared__ float sB[BK][BN];
  int t = threadIdx.x;
  int n0 = blockIdx.x * BN;
  int m0 = blockIdx.y * BM;
  int tx = t & 15, ty = t >> 4;
  float acc[4][4] = {{0.f,0.f,0.f,0.f},{0.f,0.f,0.f,0.f},{0.f,0.f,0.f,0.f},{0.f,0.f,0.f,0.f}};

  for (int pass = 0; pass < 2; ++pass) {
    const float* A = pass ? A2 : A1;
    const float* W = pass ? W2 : W1;
    if (A == nullptr) break;
    for (int k0 = 0; k0 < K; k0 += BK) {
      #pragma unroll
      for (int i = 0; i < 4; ++i) {
        int idx = t + i * 256;
        int r = idx >> 4, kk = idx & 15;
        sA[r][kk] = A[(size_t)(m0 + r) * K + k0 + kk];
      }
      #pragma unroll
      for (int i = 0; i < 4; ++i) {
        int idx = t + i * 256;
        int kk = idx >> 6, c = idx & 63;
        sB[kk][c] = W[(size_t)(k0 + kk) * H + n0 + c];
      }
      __syncthreads();
      #pragma unroll
      for (int kk = 0; kk < BK; ++kk) {
        float4 b4 = *(const float4*)&sB[kk][tx * 4];
        float a0 = sA[ty * 4 + 0][kk];
        float a1 = sA[ty * 4 + 1][kk];
        float a2 = sA[ty * 4 + 2][kk];
        float a3 = sA[ty * 4 + 3][kk];
        acc[0][0] = fmaf(a0, b4.x, acc[0][0]); acc[0][1] = fmaf(a0, b4.y, acc[0][1]);
        acc[0][2] = fmaf(a0, b4.z, acc[0][2]); acc[0][3] = fmaf(a0, b4.w, acc[0][3]);
        acc[1][0] = fmaf(a1, b4.x, acc[1][0]); acc[1][1] = fmaf(a1, b4.y, acc[1][1]);
        acc[1][2] = fmaf(a1, b4.z, acc[1][2]); acc[1][3] = fmaf(a1, b4.w, acc[1][3]);
        acc[2][0] = fmaf(a2, b4.x, acc[2][0]); acc[2][1] = fmaf(a2, b4.y, acc[2][1]);
        acc[2][2] = fmaf(a2, b4.z, acc[2][2]); acc[2][3] = fmaf(a2, b4.w, acc[2][3]);
        acc[3][0] = fmaf(a3, b4.x, acc[3][0]); acc[3][1] = fmaf(a3, b4.y, acc[3][1]);
        acc[3][2] = fmaf(a3, b4.z, acc[3][2]); acc[3][3] = fmaf(a3, b4.w, acc[3][3]);
      }
      __syncthreads();
    }
  }

  #pragma unroll
  for (int i = 0; i < 4; ++i) {
    int row = m0 + ty * 4 + i;
    int bb = row >> 10;  // row / S
    #pragma unroll
    for (int j = 0; j < 4; ++j) {
      int col = n0 + tx * 4 + j;
      float v = acc[i][j];
      if (bias) v += bias[col];
      if (perbatch) v += perbatch[bb * H + col];
      if (act) v = tanhf(v);
      C[(size_t)row * H + col] = v;
    }
  }
}

// ======================= attention =======================
// One block = 8 query rows of one (b,h). Full-row softmax (S=1024 scores in LDS).
#define AROWS 8
__global__ __launch_bounds__(256) void attn_k(
    const float* __restrict__ Q, const float* __restrict__ K,
    const float* __restrict__ V, float* __restrict__ O)
{
  __shared__ float sq[AROWS][64];
  __shared__ float sc[AROWS][S];
  __shared__ float srow[AROWS];
  int t = threadIdx.x;
  const int nb = S / AROWS;  // 128
  int blk = blockIdx.x;      // B*12*nb = 3072
  int b = blk / (12 * nb);
  int rem = blk % (12 * nb);
  int h = rem / nb;
  int i0 = (rem % nb) * AROWS;

  const float* Qp = Q + (size_t)b * S * H + (size_t)h * 64;
  for (int idx = t; idx < AROWS * 64; idx += 256) {
    int r = idx >> 6, d = idx & 63;
    sq[r][d] = Qp[(size_t)(i0 + r) * H + d];
  }
  __syncthreads();

  const float* Kp = K + (size_t)b * S * H + (size_t)h * 64;
  const float scale = 0.125f;  // 1/sqrt(64)
  for (int j = t; j < S; j += 256) {
    const float4* krow = (const float4*)&Kp[(size_t)j * H];
    float accr[AROWS] = {0.f,0.f,0.f,0.f,0.f,0.f,0.f,0.f};
    #pragma unroll
    for (int c = 0; c < 16; ++c) {
      float4 kv = krow[c];
      #pragma unroll
      for (int r = 0; r < AROWS; ++r) {
        float4 qv = *(const float4*)&sq[r][c * 4];
        accr[r] += qv.x * kv.x + qv.y * kv.y + qv.z * kv.z + qv.w * kv.w;
      }
    }
    #pragma unroll
    for (int r = 0; r < AROWS; ++r) sc[r][j] = accr[r] * scale;
  }
  __syncthreads();

  // per-row softmax: 32-lane group per row
  {
    int r = t >> 5, lane = t & 31;
    float m = -1e30f;
    for (int j = lane; j < S; j += 32) m = fmaxf(m, sc[r][j]);
    #pragma unroll
    for (int o = 16; o; o >>= 1) m = fmaxf(m, __shfl_xor(m, o));
    float s = 0.f;
    for (int j = lane; j < S; j += 32) {
      float e = __expf(sc[r][j] - m);
      sc[r][j] = e;
      s += e;
    }
    #pragma unroll
    for (int o = 16; o; o >>= 1) s += __shfl_xor(s, o);
    if (lane == 0) srow[r] = 1.0f / s;
  }
  __syncthreads();

  // PV: thread (r0, d) handles rows r0 and r0+4
  const float* Vp = V + (size_t)b * S * H + (size_t)h * 64;
  int d = t & 63, r0 = t >> 6;
  float acc0 = 0.f, acc1 = 0.f;
  for (int j = 0; j < S; ++j) {
    float v = Vp[(size_t)j * H + d];
    acc0 = fmaf(sc[r0][j], v, acc0);
    acc1 = fmaf(sc[r0 + 4][j], v, acc1);
  }
  float* Op = O + (size_t)b * S * H + (size_t)h * 64;
  Op[(size_t)(i0 + r0) * H + d] = acc0 * srow[r0];
  Op[(size_t)(i0 + r0 + 4) * H + d] = acc1 * srow[r0 + 4];
}

// ======================= softmax over sequence axis (axis=1) =======================
// One block per (b, c) column. O[b,s,c] = mult * softmax_s(Z[b,s,c])
// mult = mulvec[b,c] if mulvec else mulmat[b,s,c]
__global__ __launch_bounds__(256) void colsm_k(
    const float* __restrict__ Z, const float* __restrict__ mulvec,
    const float* __restrict__ mulmat, float* __restrict__ O)
{
  __shared__ float red[256];
  int b = blockIdx.x / H;
  int c = blockIdx.x % H;
  int t = threadIdx.x;
  const float* zp = Z + (size_t)b * S * H + c;
  float vals[4];
  float m = -1e30f;
  #pragma unroll
  for (int i = 0; i < 4; ++i) {
    vals[i] = zp[(size_t)(t + i * 256) * H];
    m = fmaxf(m, vals[i]);
  }
  red[t] = m; __syncthreads();
  for (int st = 128; st; st >>= 1) { if (t < st) red[t] = fmaxf(red[t], red[t + st]); __syncthreads(); }
  m = red[0]; __syncthreads();
  float s = 0.f;
  #pragma unroll
  for (int i = 0; i < 4; ++i) { vals[i] = __expf(vals[i] - m); s += vals[i]; }
  red[t] = s; __syncthreads();
  for (int st = 128; st; st >>= 1) { if (t < st) red[t] += red[t + st]; __syncthreads(); }
  float inv = 1.0f / red[0];
  float* op = O + (size_t)b * S * H + c;
  #pragma unroll
  for (int i = 0; i < 4; ++i) {
    int srowi = t + i * 256;
    float mult = mulvec ? mulvec[b * H + c] : mulmat[(size_t)(b * S + srowi) * H + c];
    op[(size_t)srowi * H] = mult * vals[i] * inv;
  }
}

// ======================= gate + fusion =======================
// per token: g = sigmoid(sum_c DF[c]*GW[c] + VF[c]*GW[H+c]); FU = g*VF + (1-g)*DF
__global__ __launch_bounds__(256) void gatefuse_k(
    const float* __restrict__ DF, const float* __restrict__ VF,
    const float* __restrict__ GW, float* __restrict__ FU)
{
  __shared__ float red[256];
  int tok = blockIdx.x;
  int t = threadIdx.x;
  const float* df = DF + (size_t)tok * H;
  const float* vf = VF + (size_t)tok * H;
  float dv[3], vv[3];
  float p = 0.f;
  #pragma unroll
  for (int i = 0; i < 3; ++i) {
    int c = t + i * 256;
    dv[i] = df[c]; vv[i] = vf[c];
    p = fmaf(dv[i], GW[c], p);
    p = fmaf(vv[i], GW[H + c], p);
  }
  red[t] = p; __syncthreads();
  for (int st = 128; st; st >>= 1) { if (t < st) red[t] += red[t + st]; __syncthreads(); }
  float g = 1.0f / (1.0f + __expf(-red[0]));
  float* fu = FU + (size_t)tok * H;
  #pragma unroll
  for (int i = 0; i < 3; ++i) {
    int c = t + i * 256;
    fu[c] = g * vv[i] + (1.0f - g) * dv[i];
  }
}

// ======================= nf + final output =======================
// per token: nf = sigmoid(sum_c VAN[c]*NW[c] + NP[c]*NW[H+c]); out = nf * tanh(FP)
__global__ __launch_bounds__(256) void nffinal_k(
    const float* __restrict__ VAN, const float* __restrict__ NP,
    const float* __restrict__ NW, const float* __restrict__ FP,
    float* __restrict__ OUT)
{
  __shared__ float red[256];
  int tok = blockIdx.x;
  int t = threadIdx.x;
  const float* va = VAN + (size_t)tok * H;
  const float* np = NP + (size_t)tok * H;
  float p = 0.f;
  #pragma unroll
  for (int i = 0; i < 3; ++i) {
    int c = t + i * 256;
    p = fmaf(va[c], NW[c], p);
    p = fmaf(np[c], NW[H + c], p);
  }
  red[t] = p; __syncthreads();
  for (int st = 128; st; st >>= 1) { if (t < st) red[t] += red[t + st]; __syncthreads(); }
  float nf = 1.0f / (1.0f + __expf(-red[0]));
  const float* fp = FP + (size_t)tok * H;
  float* o = OUT + (size_t)tok * H;
  #pragma unroll
  for (int i = 0; i < 3; ++i) {
    int c = t + i * 256;
    o[c] = nf * tanhf(fp[c]);
  }
}

// ======================= launch =======================
extern "C" void kernel_launch(void* const* d_in, const int* in_sizes, int n_in,
                              void* d_out, int out_size, void* d_ws, size_t ws_size,
                              hipStream_t stream) {
  const float* x        = (const float*)d_in[0];
  const float* y        = (const float*)d_in[1];
  const float* vq_w     = (const float*)d_in[2];
  const float* vq_b     = (const float*)d_in[3];
  const float* vk_w     = (const float*)d_in[4];
  const float* vk_b     = (const float*)d_in[5];
  const float* vv_w     = (const float*)d_in[6];
  const float* vv_b     = (const float*)d_in[7];
  // d_in[8..11] = dq_w, dq_b, dk_w, dk_b -- provably unused (uniform softmax)
  const float* dv_w     = (const float*)d_in[12];
  const float* dv_b     = (const float*)d_in[13];
  const float* van_fc_w = (const float*)d_in[14];
  const float* van_fc_b = (const float*)d_in[15];
  const float* WD_w     = (const float*)d_in[16];
  const float* d_theta_w= (const float*)d_in[17];
  const float* d_theta_b= (const float*)d_in[18];
  const float* WV_w     = (const float*)d_in[19];
  const float* diff_fc_w= (const float*)d_in[20];
  const float* diff_fc_b= (const float*)d_in[21];
  const float* v_gamma_w= (const float*)d_in[22];
  const float* v_gamma_b= (const float*)d_in[23];
  const float* diff_out_w=(const float*)d_in[24];
  const float* diff_out_b=(const float*)d_in[25];
  const float* van_out_w= (const float*)d_in[26];
  const float* van_out_b= (const float*)d_in[27];
  const float* diff_fus_w=(const float*)d_in[28];
  const float* diff_fus_b=(const float*)d_in[29];
  const float* van_fus_w= (const float*)d_in[30];
  const float* van_fus_b= (const float*)d_in[31];
  const float* gate_w   = (const float*)d_in[32];
  const float* nf_w     = (const float*)d_in[33];
  const float* nf_b     = (const float*)d_in[34];
  const float* nf_out_w = (const float*)d_in[35];
  const float* final_w  = (const float*)d_in[36];
  const float* final_b  = (const float*)d_in[37];
  float* out = (float*)d_out;

  float* ws = (float*)d_ws;
  const size_t TH = (size_t)T * H;
  float* B0 = ws;            // Q -> tv -> gA -> diff_fusion -> final_pre
  float* B1 = ws + TH;       // K -> z1 -> diff_out -> fusion
  float* B2 = ws + 2 * TH;   // V -> d_theta -> van_out -> nf_pre
  float* B3 = ws + 3 * TH;   // van_vector (live to the end)
  float* B4 = ws + 4 * TH;   // gB -> van_fusion
  float* B5 = ws + 5 * TH;   // z2 -> a_gamma (in place)
  float* smem = ws + 6 * TH;
  float* ybar  = smem;           // 1536
  float* dvbar = smem + 1536;    // 1536 (diff_vector per batch)
  float* wd    = smem + 3072;    // 1536
  float* c1    = smem + 4608;    // 1536
  float* c2    = smem + 6144;    // 1536

  dim3 gg(H / BN, T / BM);  // (12, 32)
  const size_t HH = (size_t)H * H;

  // per-batch constant chain (differential path collapses to GEMVs)
  meany_k<<<6, 256, 0, stream>>>(y, ybar);
  gemv_k<<<6, 256, 0, stream>>>(ybar, dv_w, dv_b, dvbar, 0);        // diff_vector[b,:]
  gemv_k<<<6, 256, 0, stream>>>(dvbar, WD_w, nullptr, wd, 1);       // tanh(diff@WD)
  gemv_k<<<6, 256, 0, stream>>>(wd, d_theta_w, d_theta_b, c1, 0);   // + top-half of d_theta_w
  gemv_k<<<6, 256, 0, stream>>>(dvbar, diff_out_w, diff_out_b, c2, 0); // top-half of diff_out_w

  // Q, K, V projections
  gemm_k<<<gg, 256, 0, stream>>>(x, vq_w, nullptr, nullptr, vq_b, nullptr, B0, H, 0);
  gemm_k<<<gg, 256, 0, stream>>>(y, vk_w, nullptr, nullptr, vk_b, nullptr, B1, H, 0);
  gemm_k<<<gg, 256, 0, stream>>>(y, vv_w, nullptr, nullptr, vv_b, nullptr, B2, H, 0);

  // vanilla attention -> van_vector (B3)
  attn_k<<<BATCH * 12 * (S / AROWS), 256, 0, stream>>>(B0, B1, B2, B3);

  // tv = tanh(van@van_fc + b)
  gemm_k<<<gg, 256, 0, stream>>>(B3, van_fc_w, nullptr, nullptr, van_fc_b, nullptr, B0, H, 1);
  // z1 = tv@d_theta_w[H:2H] + c1[b,:]
  gemm_k<<<gg, 256, 0, stream>>>(B0, d_theta_w + HH, nullptr, nullptr, nullptr, c1, B1, H, 0);
  // d_theta = dvbar * softmax_axis1(z1)
  colsm_k<<<BATCH * H, 256, 0, stream>>>(B1, dvbar, nullptr, B2);
  // gA = tanh(van@WV)
  gemm_k<<<gg, 256, 0, stream>>>(B3, WV_w, nullptr, nullptr, nullptr, nullptr, B0, H, 1);
  // gB = tanh(d_theta@diff_fc + b)
  gemm_k<<<gg, 256, 0, stream>>>(B2, diff_fc_w, nullptr, nullptr, diff_fc_b, nullptr, B4, H, 1);
  // z2 = gA@v_gamma[0:H] + gB@v_gamma[H:2H] + b
  gemm_k<<<gg, 256, 0, stream>>>(B0, v_gamma_w, B4, v_gamma_w + HH, v_gamma_b, nullptr, B5, H, 0);
  // a_gamma = van * softmax_axis1(z2)  (in place on B5)
  colsm_k<<<BATCH * H, 256, 0, stream>>>(B5, nullptr, B3, B5);
  // diff_out = tanh(d_theta@diff_out_w[H:2H] + c2[b,:])
  gemm_k<<<gg, 256, 0, stream>>>(B2, diff_out_w + HH, nullptr, nullptr, nullptr, c2, B1, H, 1);
  // van_out = tanh(van@van_out[0:H] + a_gamma@van_out[H:2H] + b)
  gemm_k<<<gg, 256, 0, stream>>>(B3, van_out_w, B5, van_out_w + HH, van_out_b, nullptr, B2, H, 1);
  // diff_fusion = tanh(diff_out@diff_fus + b)
  gemm_k<<<gg, 256, 0, stream>>>(B1, diff_fus_w, nullptr, nullptr, diff_fus_b, nullptr, B0, H, 1);
  // van_fusion = tanh(van_out@van_fus + b)
  gemm_k<<<gg, 256, 0, stream>>>(B2, van_fus_w, nullptr, nullptr, van_fus_b, nullptr, B4, H, 1);
  // gate + fusion -> B1
  gatefuse_k<<<T, 256, 0, stream>>>(B0, B4, gate_w, B1);
  // nf_pre = fusion@nf_w + nf_b
  gemm_k<<<gg, 256, 0, stream>>>(B1, nf_w, nullptr, nullptr, nf_b, nullptr, B2, H, 0);
  // final_pre = fusion@final_w + final_b
  gemm_k<<<gg, 256, 0, stream>>>(B1, final_w, nullptr, nullptr, final_b, nullptr, B0, H, 0);
  // out = sigmoid(van.nf_top + nf_pre.nf_bot) * tanh(final_pre)
  nffinal_k<<<T, 256, 0, stream>>>(B3, B2, nf_out_w, B0, out);
}

// Round 2
// 545.523 us; speedup vs baseline: 3.8331x; 3.8331x over previous
//
#include <hip/hip_runtime.h>
#include <hip/hip_bf16.h>
#include <math.h>

#define H 768
#define S 1024
#define BATCH 2
#define T 2048  // BATCH*S
#define TH ((size_t)T * H)

typedef unsigned short u16;
typedef __attribute__((ext_vector_type(8))) short short8;
typedef __attribute__((ext_vector_type(4))) float f32x4;

__device__ __forceinline__ u16 f2b(float f) {
  __hip_bfloat16 h = __float2bfloat16(f);
  return *reinterpret_cast<u16*>(&h);
}
__device__ __forceinline__ float b2f(u16 u) {
  __hip_bfloat16 h = *reinterpret_cast<__hip_bfloat16*>(&u);
  return __bfloat162float(h);
}

// ======================= f32 -> bf16 conversion =======================
__global__ __launch_bounds__(256) void cvt_k(const float* __restrict__ X, u16* __restrict__ O) {
  int i = blockIdx.x * 256 + threadIdx.x;   // grid sized exactly: TH/8 / 256
  float4 a = ((const float4*)X)[2 * i];
  float4 b = ((const float4*)X)[2 * i + 1];
  u16 tmp[8] = {f2b(a.x), f2b(a.y), f2b(a.z), f2b(a.w), f2b(b.x), f2b(b.y), f2b(b.z), f2b(b.w)};
  ((uint4*)O)[i] = *(uint4*)tmp;
}

// ======================= weight transpose+convert: W[K][768] -> Wt[768][K] bf16 ===========
struct WprepArgs {
  const float* src[14];
  unsigned dst[14];
  int ktiles[14];
  int tstart[15];
};
__global__ __launch_bounds__(256) void wprep_k(WprepArgs a, u16* __restrict__ wt) {
  __shared__ float sT[64][68];
  int blk = blockIdx.x;
  int mi = 0;
  while (blk >= a.tstart[mi + 1]) ++mi;
  int local = blk - a.tstart[mi];
  int kt = a.ktiles[mi];
  int tn = local / kt, tk = local % kt;
  int K = kt * 64;
  const float* W = a.src[mi];
  u16* D = wt + a.dst[mi];
  int t = threadIdx.x;
  int r = t >> 2, c = (t & 3) * 16;
  const float4* srcp = (const float4*)(W + ((size_t)(tk * 64 + r)) * H + tn * 64 + c);
  float4 v0 = srcp[0], v1 = srcp[1], v2 = srcp[2], v3 = srcp[3];
  *(float4*)&sT[r][c] = v0; *(float4*)&sT[r][c + 4] = v1;
  *(float4*)&sT[r][c + 8] = v2; *(float4*)&sT[r][c + 12] = v3;
  __syncthreads();
  int n = t >> 2, kk = (t & 3) * 16;
  u16 tmp[16];
  #pragma unroll
  for (int j = 0; j < 16; ++j) tmp[j] = f2b(sT[kk + j][n]);
  uint4* dst = (uint4*)(D + ((size_t)(tn * 64 + n)) * K + tk * 64 + kk);
  dst[0] = *(uint4*)&tmp[0];
  dst[1] = *(uint4*)&tmp[8];
}

// ======================= small f32 kernels (differential path) =======================
__global__ __launch_bounds__(256) void meany_k(const float* __restrict__ Y, float* __restrict__ ybar) {
  int t = blockIdx.x * 256 + threadIdx.x;
  int b = t / H, c = t % H;
  const float* yp = Y + (size_t)b * S * H + c;
  float s = 0.f;
  for (int j = 0; j < S; ++j) s += yp[(size_t)j * H];
  ybar[t] = s * (1.0f / (float)S);
}

__global__ __launch_bounds__(256) void gemv_k(const float* __restrict__ A, const float* __restrict__ W,
                                              const float* __restrict__ bias, float* __restrict__ O, int act) {
  int t = blockIdx.x * 256 + threadIdx.x;
  int b = t / H, n = t % H;
  const float* a = A + b * H;
  float s = bias ? bias[n] : 0.f;
  for (int k = 0; k < H; ++k) s = fmaf(a[k], W[(size_t)k * H + n], s);
  if (act) s = tanhf(s);
  O[t] = s;
}

// ======================= bf16 MFMA GEMM =======================
// C(T x 768) = act( A1(bf16,[T][768]) @ W1t^T + [A2 @ W2t^T] + bias + perbatch )
// Wt layout: [768 n][ldw k] bf16 (transposed weights). out: bf16 Cb and/or f32 Cf.
__global__ __launch_bounds__(256) void bgemm_k(
    const u16* __restrict__ A1, const u16* __restrict__ W1, int ldw1,
    const u16* __restrict__ A2, const u16* __restrict__ W2, int ldw2,
    const float* __restrict__ bias, const float* __restrict__ perbatch,
    u16* __restrict__ Cb, float* __restrict__ Cf, int act)
{
  __shared__ u16 sA[64 * 64];
  __shared__ u16 sB[64 * 64];
  int t = threadIdx.x;
  int n0 = blockIdx.x * 64;
  int m0 = blockIdx.y * 64;
  int w = t >> 6, l = t & 63, lr = l & 15, lg = l >> 4;
  int wr = (w >> 1) * 32, wc = (w & 1) * 32;

  f32x4 acc[2][2];
  #pragma unroll
  for (int i = 0; i < 2; ++i)
    #pragma unroll
    for (int j = 0; j < 2; ++j) acc[i][j] = (f32x4){0.f, 0.f, 0.f, 0.f};

  int id0 = t, id1 = t + 256;
  int r0 = id0 >> 3, c0 = id0 & 7;
  int r1 = id1 >> 3, c1 = id1 & 7;

  for (int pass = 0; pass < 2; ++pass) {
    const u16* A = pass ? A2 : A1;
    const u16* W = pass ? W2 : W1;
    int ldw = pass ? ldw2 : ldw1;
    if (A == nullptr) break;
    for (int k0 = 0; k0 < H; k0 += 64) {
      uint4 a0 = *(const uint4*)(A + ((size_t)(m0 + r0)) * H + k0 + 8 * c0);
      uint4 a1 = *(const uint4*)(A + ((size_t)(m0 + r1)) * H + k0 + 8 * c1);
      uint4 b0 = *(const uint4*)(W + ((size_t)(n0 + r0)) * ldw + k0 + 8 * c0);
      uint4 b1 = *(const uint4*)(W + ((size_t)(n0 + r1)) * ldw + k0 + 8 * c1);
      if (k0 || pass) __syncthreads();  // previous compute done before overwrite
      *(uint4*)(sA + r0 * 64 + 8 * (c0 ^ (r0 & 7))) = a0;
      *(uint4*)(sA + r1 * 64 + 8 * (c1 ^ (r1 & 7))) = a1;
      *(uint4*)(sB + r0 * 64 + 8 * (c0 ^ (r0 & 7))) = b0;
      *(uint4*)(sB + r1 * 64 + 8 * (c1 ^ (r1 & 7))) = b1;
      __syncthreads();
      #pragma unroll
      for (int kh = 0; kh < 2; ++kh) {
        short8 af[2], bf[2];
        #pragma unroll
        for (int mi = 0; mi < 2; ++mi) {
          int row = wr + 16 * mi + lr;
          af[mi] = *(const short8*)(sA + row * 64 + 8 * ((4 * kh + lg) ^ (row & 7)));
        }
        #pragma unroll
        for (int ni = 0; ni < 2; ++ni) {
          int row = wc + 16 * ni + lr;
          bf[ni] = *(const short8*)(sB + row * 64 + 8 * ((4 * kh + lg) ^ (row & 7)));
        }
        #pragma unroll
        for (int mi = 0; mi < 2; ++mi)
          #pragma unroll
          for (int ni = 0; ni < 2; ++ni)
            acc[mi][ni] = __builtin_amdgcn_mfma_f32_16x16x32_bf16(af[mi], bf[ni], acc[mi][ni], 0, 0, 0);
      }
    }
  }

  // epilogue: D row(M) = lg*4+reg, col(N) = lr  (within each 16x16)
  #pragma unroll
  for (int mi = 0; mi < 2; ++mi) {
    #pragma unroll
    for (int reg = 0; reg < 4; ++reg) {
      int row = m0 + wr + 16 * mi + lg * 4 + reg;
      int bb = row >> 10;
      #pragma unroll
      for (int ni = 0; ni < 2; ++ni) {
        int col = n0 + wc + 16 * ni + lr;
        float v = acc[mi][ni][reg];
        if (bias) v += bias[col];
        if (perbatch) v += perbatch[bb * H + col];
        if (act) v = tanhf(v);
        if (Cb) Cb[(size_t)row * H + col] = f2b(v);
        if (Cf) Cf[(size_t)row * H + col] = v;
      }
    }
  }
}

// ======================= head transpose: V[T][768] -> VT[B*12][64][1024] ===========
__global__ __launch_bounds__(256) void headT_k(const u16* __restrict__ V, u16* __restrict__ VT) {
  __shared__ u16 sT[64][72];
  int t = threadIdx.x;
  int blk = blockIdx.x;  // b*192 + h*16 + st
  int b = blk / 192; int rem = blk % 192; int h = rem / 16; int s0 = (rem % 16) * 64;
  int r = t >> 2, c = (t & 3) * 16;
  const uint4* src = (const uint4*)(V + ((size_t)(b * 1024 + s0 + r)) * H + h * 64 + c);
  uint4 v0 = src[0], v1 = src[1];
  *(uint4*)&sT[r][c] = v0;
  *(uint4*)&sT[r][c + 8] = v1;
  __syncthreads();
  int d = t >> 2, sc = (t & 3) * 16;
  u16 tmp[16];
  #pragma unroll
  for (int j = 0; j < 16; ++j) tmp[j] = sT[sc + j][d];
  uint4* dst = (uint4*)(VT + ((size_t)((b * 12 + h) * 64 + d)) * 1024 + s0 + sc);
  dst[0] = *(uint4*)&tmp[0];
  dst[1] = *(uint4*)&tmp[8];
}

// ======================= MFMA flash attention =======================
// block: one (b,h), 64 q rows; wave w owns q rows [16w,16w+16). 16 KV tiles of 64.
__global__ __launch_bounds__(256) void mattn_k(
    const u16* __restrict__ Q, const u16* __restrict__ Kg,
    const u16* __restrict__ VT, u16* __restrict__ O)
{
  __shared__ u16 sQ[64 * 64];
  __shared__ u16 sK[64 * 64];
  __shared__ u16 sV[64 * 64];   // V^T tile: rows=d, cols=kv
  __shared__ u16 sP[4 * 16 * 64];
  int t = threadIdx.x;
  int w = t >> 6, l = t & 63, lr = l & 15, lg = l >> 4;
  int blk = blockIdx.x;  // b*192 + h*16 + qt
  int b = blk / 192; int rem = blk % 192; int h = rem / 16; int q0 = (rem % 16) * 64;

  #pragma unroll
  for (int i = 0; i < 2; ++i) {
    int id = t + i * 256; int r = id >> 3, c = id & 7;
    uint4 v = *(const uint4*)(Q + ((size_t)(b * 1024 + q0 + r)) * H + h * 64 + 8 * c);
    *(uint4*)(sQ + r * 64 + 8 * (c ^ (r & 7))) = v;
  }

  f32x4 oacc[4];
  #pragma unroll
  for (int i = 0; i < 4; ++i) oacc[i] = (f32x4){0.f, 0.f, 0.f, 0.f};
  float mrow[4], lrow[4];
  #pragma unroll
  for (int i = 0; i < 4; ++i) { mrow[i] = -1e30f; lrow[i] = 0.f; }
  __syncthreads();

  for (int kt = 0; kt < 16; ++kt) {
    int kv0 = kt * 64;
    #pragma unroll
    for (int i = 0; i < 2; ++i) {
      int id = t + i * 256; int r = id >> 3, c = id & 7;
      uint4 kv = *(const uint4*)(Kg + ((size_t)(b * 1024 + kv0 + r)) * H + h * 64 + 8 * c);
      uint4 vv = *(const uint4*)(VT + ((size_t)((b * 12 + h) * 64 + r)) * 1024 + kv0 + 8 * c);
      *(uint4*)(sK + r * 64 + 8 * (c ^ (r & 7))) = kv;
      *(uint4*)(sV + r * 64 + 8 * (c ^ (r & 7))) = vv;
    }
    __syncthreads();

    // S = Q K^T  (wave strip 16 q-rows x 64 kv-cols)
    f32x4 sacc[4];
    #pragma unroll
    for (int i = 0; i < 4; ++i) sacc[i] = (f32x4){0.f, 0.f, 0.f, 0.f};
    #pragma unroll
    for (int kh = 0; kh < 2; ++kh) {
      int qrow = 16 * w + lr;
      short8 qf = *(const short8*)(sQ + qrow * 64 + 8 * ((4 * kh + lg) ^ (qrow & 7)));
      #pragma unroll
      for (int ns = 0; ns < 4; ++ns) {
        int krow = 16 * ns + lr;
        short8 kf = *(const short8*)(sK + krow * 64 + 8 * ((4 * kh + lg) ^ (krow & 7)));
        sacc[ns] = __builtin_amdgcn_mfma_f32_16x16x32_bf16(qf, kf, sacc[ns], 0, 0, 0);
      }
    }

    // online softmax; lane's rows are q = lg*4+r; cols kv = 16*ns + lr
    #pragma unroll
    for (int r = 0; r < 4; ++r) {
      float mx = fmaxf(fmaxf(sacc[0][r], sacc[1][r]), fmaxf(sacc[2][r], sacc[3][r]));
      mx *= 0.125f;
      #pragma unroll
      for (int off = 1; off < 16; off <<= 1) mx = fmaxf(mx, __shfl_xor(mx, off));
      float mnew = fmaxf(mrow[r], mx);
      float resc = __expf(mrow[r] - mnew);
      mrow[r] = mnew;
      float psum = 0.f;
      int q = lg * 4 + r;
      #pragma unroll
      for (int ns = 0; ns < 4; ++ns) {
        float p = __expf(sacc[ns][r] * 0.125f - mnew);
        psum += p;
        int kv = 16 * ns + lr;
        unsigned byteoff = (unsigned)(w * 2048 + q * 128 + ((kv * 2) ^ ((q & 7) << 4)));
        *(u16*)((char*)sP + byteoff) = f2b(p);
      }
      #pragma unroll
      for (int off = 1; off < 16; off <<= 1) psum += __shfl_xor(psum, off);
      lrow[r] = lrow[r] * resc + psum;
      oacc[0][r] *= resc; oacc[1][r] *= resc; oacc[2][r] *= resc; oacc[3][r] *= resc;
    }

    // O += P V   (A = P from sP, B^T = V^T rows = d)
    #pragma unroll
    for (int kh = 0; kh < 2; ++kh) {
      short8 pf = *(const short8*)((char*)sP + w * 2048 + lr * 128 + (((4 * kh + lg) << 4) ^ ((lr & 7) << 4)));
      #pragma unroll
      for (int ds = 0; ds < 4; ++ds) {
        int vrow = 16 * ds + lr;
        short8 vf = *(const short8*)(sV + vrow * 64 + 8 * ((4 * kh + lg) ^ (vrow & 7)));
        oacc[ds] = __builtin_amdgcn_mfma_f32_16x16x32_bf16(pf, vf, oacc[ds], 0, 0, 0);
      }
    }
    __syncthreads();
  }

  #pragma unroll
  for (int r = 0; r < 4; ++r) {
    float inv = 1.0f / lrow[r];
    int qrow = q0 + 16 * w + lg * 4 + r;
    #pragma unroll
    for (int ds = 0; ds < 4; ++ds) {
      int d = 16 * ds + lr;
      O[((size_t)(b * 1024 + qrow)) * H + h * 64 + d] = f2b(oacc[ds][r] * inv);
    }
  }
}

// ======================= softmax over sequence axis (bf16 io) =======================
__global__ __launch_bounds__(256) void colsm_k(
    const u16* __restrict__ Z, const float* __restrict__ mulvec,
    const u16* __restrict__ mulmat, u16* __restrict__ O)
{
  __shared__ float red[256];
  int b = blockIdx.x / H;
  int c = blockIdx.x % H;
  int t = threadIdx.x;
  const u16* zp = Z + (size_t)b * S * H + c;
  float vals[4];
  float m = -1e30f;
  #pragma unroll
  for (int i = 0; i < 4; ++i) {
    vals[i] = b2f(zp[(size_t)(t + i * 256) * H]);
    m = fmaxf(m, vals[i]);
  }
  red[t] = m; __syncthreads();
  for (int st = 128; st; st >>= 1) { if (t < st) red[t] = fmaxf(red[t], red[t + st]); __syncthreads(); }
  m = red[0]; __syncthreads();
  float s = 0.f;
  #pragma unroll
  for (int i = 0; i < 4; ++i) { vals[i] = __expf(vals[i] - m); s += vals[i]; }
  red[t] = s; __syncthreads();
  for (int st = 128; st; st >>= 1) { if (t < st) red[t] += red[t + st]; __syncthreads(); }
  float inv = 1.0f / red[0];
  u16* op = O + (size_t)b * S * H + c;
  #pragma unroll
  for (int i = 0; i < 4; ++i) {
    int srowi = t + i * 256;
    float mult = mulvec ? mulvec[b * H + c] : b2f(mulmat[(size_t)(b * S + srowi) * H + c]);
    op[(size_t)srowi * H] = f2b(mult * vals[i] * inv);
  }
}

// ======================= gate + fusion (bf16 io) =======================
__global__ __launch_bounds__(256) void gatefuse_k(
    const u16* __restrict__ DF, const u16* __restrict__ VF,
    const float* __restrict__ GW, u16* __restrict__ FU)
{
  __shared__ float red[256];
  int tok = blockIdx.x;
  int t = threadIdx.x;
  const u16* df = DF + (size_t)tok * H;
  const u16* vf = VF + (size_t)tok * H;
  float dv[3], vv[3];
  float p = 0.f;
  #pragma unroll
  for (int i = 0; i < 3; ++i) {
    int c = t + i * 256;
    dv[i] = b2f(df[c]); vv[i] = b2f(vf[c]);
    p = fmaf(dv[i], GW[c], p);
    p = fmaf(vv[i], GW[H + c], p);
  }
  red[t] = p; __syncthreads();
  for (int st = 128; st; st >>= 1) { if (t < st) red[t] += red[t + st]; __syncthreads(); }
  float g = 1.0f / (1.0f + __expf(-red[0]));
  u16* fu = FU + (size_t)tok * H;
  #pragma unroll
  for (int i = 0; i < 3; ++i) {
    int c = t + i * 256;
    fu[c] = f2b(g * vv[i] + (1.0f - g) * dv[i]);
  }
}

// ======================= nf + final output =======================
__global__ __launch_bounds__(256) void nffinal_k(
    const u16* __restrict__ VAN, const float* __restrict__ NP,
    const float* __restrict__ NW, const float* __restrict__ FP,
    float* __restrict__ OUT)
{
  __shared__ float red[256];
  int tok = blockIdx.x;
  int t = threadIdx.x;
  const u16* va = VAN + (size_t)tok * H;
  const float* np = NP + (size_t)tok * H;
  float p = 0.f;
  #pragma unroll
  for (int i = 0; i < 3; ++i) {
    int c = t + i * 256;
    p = fmaf(b2f(va[c]), NW[c], p);
    p = fmaf(np[c], NW[H + c], p);
  }
  red[t] = p; __syncthreads();
  for (int st = 128; st; st >>= 1) { if (t < st) red[t] += red[t + st]; __syncthreads(); }
  float nf = 1.0f / (1.0f + __expf(-red[0]));
  const float* fp = FP + (size_t)tok * H;
  float* o = OUT + (size_t)tok * H;
  #pragma unroll
  for (int i = 0; i < 3; ++i) {
    int c = t + i * 256;
    o[c] = nf * tanhf(fp[c]);
  }
}

// ======================= launch =======================
extern "C" void kernel_launch(void* const* d_in, const int* in_sizes, int n_in,
                              void* d_out, int out_size, void* d_ws, size_t ws_size,
                              hipStream_t stream) {
  const float* x        = (const float*)d_in[0];
  const float* y        = (const float*)d_in[1];
  const float* vq_w     = (const float*)d_in[2];
  const float* vq_b     = (const float*)d_in[3];
  const float* vk_w     = (const float*)d_in[4];
  const float* vk_b     = (const float*)d_in[5];
  const float* vv_w     = (const float*)d_in[6];
  const float* vv_b     = (const float*)d_in[7];
  // d_in[8..11] = dq_w, dq_b, dk_w, dk_b -- unused (uniform softmax over constant rows)
  const float* dv_w     = (const float*)d_in[12];
  const float* dv_b     = (const float*)d_in[13];
  const float* van_fc_w = (const float*)d_in[14];
  const float* van_fc_b = (const float*)d_in[15];
  const float* WD_w     = (const float*)d_in[16];
  const float* d_theta_w= (const float*)d_in[17];
  const float* d_theta_b= (const float*)d_in[18];
  const float* WV_w     = (const float*)d_in[19];
  const float* diff_fc_w= (const float*)d_in[20];
  const float* diff_fc_b= (const float*)d_in[21];
  const float* v_gamma_w= (const float*)d_in[22];
  const float* v_gamma_b= (const float*)d_in[23];
  const float* diff_out_w=(const float*)d_in[24];
  const float* diff_out_b=(const float*)d_in[25];
  const float* van_out_w= (const float*)d_in[26];
  const float* van_out_b= (const float*)d_in[27];
  const float* diff_fus_w=(const float*)d_in[28];
  const float* diff_fus_b=(const float*)d_in[29];
  const float* van_fus_w= (const float*)d_in[30];
  const float* van_fus_b= (const float*)d_in[31];
  const float* gate_w   = (const float*)d_in[32];
  const float* nf_w     = (const float*)d_in[33];
  const float* nf_b     = (const float*)d_in[34];
  const float* nf_out_w = (const float*)d_in[35];
  const float* final_w  = (const float*)d_in[36];
  const float* final_b  = (const float*)d_in[37];
  float* out = (float*)d_out;

  // ---- workspace layout ----
  u16* wt = (u16*)d_ws;
  const size_t HH_ = (size_t)H * H;          // 589824
  const size_t HH2 = 2 * HH_;                // 1179648 (1536x768)
  // transpose order: vq vk vv vanfc WV difffc difffus vanfus nf final | dtheta vgamma diffout vanout
  size_t woff[14];
  const float* wsrc[14] = {vq_w, vk_w, vv_w, van_fc_w, WV_w, diff_fc_w, diff_fus_w, van_fus_w,
                           nf_w, final_w, d_theta_w, v_gamma_w, diff_out_w, van_out_w};
  int wk[14] = {12,12,12,12,12,12,12,12,12,12, 24,24,24,24};  // ktiles (kdim/64)
  size_t o = 0;
  for (int i = 0; i < 14; ++i) { woff[i] = o; o += (i < 10) ? HH_ : HH2; }
  u16* bufs = wt + o;  // o = 10,616,832
  u16* bX   = bufs + 0 * TH;   // x bf16 -> tv -> gA -> van_out
  u16* bY   = bufs + 1 * TH;   // y bf16 -> z1 -> gB -> diff_fusion
  u16* bQ   = bufs + 2 * TH;   // Q -> d_theta -> van_fusion
  u16* bK   = bufs + 3 * TH;   // K -> z2/a_gamma -> fusion
  u16* bV   = bufs + 4 * TH;   // V -> diff_out
  u16* bVT  = bufs + 5 * TH;   // V^T per head
  u16* bVan = bufs + 6 * TH;   // van_vector (live to end)
  float* F0 = (float*)(bufs + 7 * TH);  // nf_pre (f32)
  float* F1 = F0 + TH;                  // final_pre (f32)
  float* sm = F1 + TH;
  float* ybar  = sm;
  float* dvbar = sm + 1536;
  float* wd    = sm + 3072;
  float* c1    = sm + 4608;
  float* c2    = sm + 6144;

  // ---- weight prep + input conversion ----
  WprepArgs wa;
  int ts = 0;
  for (int i = 0; i < 14; ++i) {
    wa.src[i] = wsrc[i];
    wa.dst[i] = (unsigned)woff[i];
    wa.ktiles[i] = wk[i];
    wa.tstart[i] = ts;
    ts += wk[i] * 12;
  }
  wa.tstart[14] = ts;  // 2592
  wprep_k<<<ts, 256, 0, stream>>>(wa, wt);
  cvt_k<<<TH / 8 / 256, 256, 0, stream>>>(x, bX);
  cvt_k<<<TH / 8 / 256, 256, 0, stream>>>(y, bY);

  // ---- differential path (per-batch constants, exact f32) ----
  meany_k<<<6, 256, 0, stream>>>(y, ybar);
  gemv_k<<<6, 256, 0, stream>>>(ybar, dv_w, dv_b, dvbar, 0);
  gemv_k<<<6, 256, 0, stream>>>(dvbar, WD_w, nullptr, wd, 1);
  gemv_k<<<6, 256, 0, stream>>>(wd, d_theta_w, d_theta_b, c1, 0);
  gemv_k<<<6, 256, 0, stream>>>(dvbar, diff_out_w, diff_out_b, c2, 0);

  dim3 gg(12, 32);
  const u16 *wt_vq = wt + woff[0], *wt_vk = wt + woff[1], *wt_vv = wt + woff[2],
            *wt_vanfc = wt + woff[3], *wt_WV = wt + woff[4], *wt_difffc = wt + woff[5],
            *wt_difffus = wt + woff[6], *wt_vanfus = wt + woff[7], *wt_nf = wt + woff[8],
            *wt_final = wt + woff[9], *wt_dtheta = wt + woff[10], *wt_vg = wt + woff[11],
            *wt_diffout = wt + woff[12], *wt_vanout = wt + woff[13];

  // ---- QKV projections ----
  bgemm_k<<<gg, 256, 0, stream>>>(bX, wt_vq, H, nullptr, nullptr, 0, vq_b, nullptr, bQ, nullptr, 0);
  bgemm_k<<<gg, 256, 0, stream>>>(bY, wt_vk, H, nullptr, nullptr, 0, vk_b, nullptr, bK, nullptr, 0);
  bgemm_k<<<gg, 256, 0, stream>>>(bY, wt_vv, H, nullptr, nullptr, 0, vv_b, nullptr, bV, nullptr, 0);
  headT_k<<<384, 256, 0, stream>>>(bV, bVT);
  mattn_k<<<384, 256, 0, stream>>>(bQ, bK, bVT, bVan);

  // ---- gating chain ----
  // tv = tanh(van@van_fc + b) -> bX
  bgemm_k<<<gg, 256, 0, stream>>>(bVan, wt_vanfc, H, nullptr, nullptr, 0, van_fc_b, nullptr, bX, nullptr, 1);
  // z1 = tv@dth[H:2H] + c1 -> bY
  bgemm_k<<<gg, 256, 0, stream>>>(bX, wt_dtheta + H, 2 * H, nullptr, nullptr, 0, nullptr, c1, bY, nullptr, 0);
  // d_theta = dvbar * softmax_axis1(z1) -> bQ
  colsm_k<<<BATCH * H, 256, 0, stream>>>(bY, dvbar, nullptr, bQ);
  // gA = tanh(van@WV) -> bX
  bgemm_k<<<gg, 256, 0, stream>>>(bVan, wt_WV, H, nullptr, nullptr, 0, nullptr, nullptr, bX, nullptr, 1);
  // gB = tanh(d_theta@diff_fc + b) -> bY
  bgemm_k<<<gg, 256, 0, stream>>>(bQ, wt_difffc, H, nullptr, nullptr, 0, diff_fc_b, nullptr, bY, nullptr, 1);
  // z2 = gA@vg1 + gB@vg2 + b -> bK
  bgemm_k<<<gg, 256, 0, stream>>>(bX, wt_vg, 2 * H, bY, wt_vg + H, 2 * H, v_gamma_b, nullptr, bK, nullptr, 0);
  // a_gamma = van * softmax_axis1(z2) -> bK (in place)
  colsm_k<<<BATCH * H, 256, 0, stream>>>(bK, nullptr, bVan, bK);
  // diff_out = tanh(d_theta@diffout[H:2H] + c2) -> bV
  bgemm_k<<<gg, 256, 0, stream>>>(bQ, wt_diffout + H, 2 * H, nullptr, nullptr, 0, nullptr, c2, bV, nullptr, 1);
  // van_out = tanh(van@vanout1 + a_gamma@vanout2 + b) -> bX
  bgemm_k<<<gg, 256, 0, stream>>>(bVan, wt_vanout, 2 * H, bK, wt_vanout + H, 2 * H, van_out_b, nullptr, bX, nullptr, 1);
  // diff_fusion = tanh(diff_out@diff_fus + b) -> bY
  bgemm_k<<<gg, 256, 0, stream>>>(bV, wt_difffus, H, nullptr, nullptr, 0, diff_fus_b, nullptr, bY, nullptr, 1);
  // van_fusion = tanh(van_out@van_fus + b) -> bQ
  bgemm_k<<<gg, 256, 0, stream>>>(bX, wt_vanfus, H, nullptr, nullptr, 0, van_fus_b, nullptr, bQ, nullptr, 1);
  // fusion -> bK
  gatefuse_k<<<T, 256, 0, stream>>>(bY, bQ, gate_w, bK);
  // nf_pre = fusion@nf + b -> F0 (f32)
  bgemm_k<<<gg, 256, 0, stream>>>(bK, wt_nf, H, nullptr, nullptr, 0, nf_b, nullptr, nullptr, F0, 0);
  // final_pre = fusion@final + b -> F1 (f32)
  bgemm_k<<<gg, 256, 0, stream>>>(bK, wt_final, H, nullptr, nullptr, 0, final_b, nullptr, nullptr, F1, 0);
  // out = sigmoid([van, nf_pre]@nf_out) * tanh(final_pre)
  nffinal_k<<<T, 256, 0, stream>>>(bVan, F0, nf_out_w, F1, out);
}

// Round 3
// 298.874 us; speedup vs baseline: 6.9964x; 1.8253x over previous
//
#include <hip/hip_runtime.h>
#include <hip/hip_bf16.h>
#include <math.h>

#define H 768
#define S 1024
#define BATCH 2
#define T 2048  // BATCH*S
#define TH ((size_t)T * H)

typedef unsigned short u16;
typedef __attribute__((ext_vector_type(8))) short short8;
typedef __attribute__((ext_vector_type(4))) float f32x4;

__device__ __forceinline__ u16 f2b(float f) {
  __hip_bfloat16 h = __float2bfloat16(f);
  return *reinterpret_cast<u16*>(&h);
}
__device__ __forceinline__ float b2f(u16 u) {
  __hip_bfloat16 h = *reinterpret_cast<__hip_bfloat16*>(&u);
  return __bfloat162float(h);
}

// ======================= f32 -> bf16 conversion =======================
__global__ __launch_bounds__(256) void cvt_k(const float* __restrict__ X, u16* __restrict__ O) {
  int i = blockIdx.x * 256 + threadIdx.x;
  float4 a = ((const float4*)X)[2 * i];
  float4 b = ((const float4*)X)[2 * i + 1];
  u16 tmp[8] = {f2b(a.x), f2b(a.y), f2b(a.z), f2b(a.w), f2b(b.x), f2b(b.y), f2b(b.z), f2b(b.w)};
  ((uint4*)O)[i] = *(uint4*)tmp;
}

// ======================= weight transpose+convert: W[K][768] -> Wt[768][K] bf16 ===========
struct WprepArgs {
  const float* src[14];
  unsigned dst[14];
  int ktiles[14];
  int tstart[15];
};
__global__ __launch_bounds__(256) void wprep_k(WprepArgs a, u16* __restrict__ wt) {
  __shared__ float sT[64][68];
  int blk = blockIdx.x;
  int mi = 0;
  while (blk >= a.tstart[mi + 1]) ++mi;
  int local = blk - a.tstart[mi];
  int kt = a.ktiles[mi];
  int tn = local / kt, tk = local % kt;
  int K = kt * 64;
  const float* W = a.src[mi];
  u16* D = wt + a.dst[mi];
  int t = threadIdx.x;
  int r = t >> 2, c = (t & 3) * 16;
  const float4* srcp = (const float4*)(W + ((size_t)(tk * 64 + r)) * H + tn * 64 + c);
  float4 v0 = srcp[0], v1 = srcp[1], v2 = srcp[2], v3 = srcp[3];
  *(float4*)&sT[r][c] = v0; *(float4*)&sT[r][c + 4] = v1;
  *(float4*)&sT[r][c + 8] = v2; *(float4*)&sT[r][c + 12] = v3;
  __syncthreads();
  int n = t >> 2, kk = (t & 3) * 16;
  u16 tmp[16];
  #pragma unroll
  for (int j = 0; j < 16; ++j) tmp[j] = f2b(sT[kk + j][n]);
  uint4* dst = (uint4*)(D + ((size_t)(tn * 64 + n)) * K + tk * 64 + kk);
  dst[0] = *(uint4*)&tmp[0];
  dst[1] = *(uint4*)&tmp[8];
}

// ======================= mean over s (2-stage, parallel) =======================
// stage1: grid 48 = b(2) x cc(3) x sc(8); partial[(sc*2+b)*H + c]
__global__ __launch_bounds__(256) void meany1_k(const float* __restrict__ Y, float* __restrict__ part) {
  int blk = blockIdx.x;
  int b = blk / 24, r = blk % 24, cc = r / 8, sc = r % 8;
  int c = cc * 256 + threadIdx.x;
  const float* yp = Y + (size_t)b * S * H + (size_t)sc * 128 * H + c;
  float s = 0.f;
  for (int j = 0; j < 128; ++j) s += yp[(size_t)j * H];
  part[(sc * 2 + b) * H + c] = s;
}
__global__ __launch_bounds__(256) void meany2_k(const float* __restrict__ part, float* __restrict__ ybar) {
  int t = blockIdx.x * 256 + threadIdx.x;  // grid 6
  float s = 0.f;
  int b = t / H, c = t % H;
  #pragma unroll
  for (int sc = 0; sc < 8; ++sc) s += part[(sc * 2 + b) * H + c];
  ybar[t] = s * (1.0f / 1024.0f);
}

// ======================= wave-per-output GEMV (2x768 = 1536 outputs) ===========
__global__ __launch_bounds__(256) void gemv_k(const float* __restrict__ A, const float* __restrict__ W,
                                              const float* __restrict__ bias, float* __restrict__ O, int act) {
  int gid = blockIdx.x * 4 + (threadIdx.x >> 6);  // 0..1535, grid 384
  int lane = threadIdx.x & 63;
  int b = gid / H, n = gid % H;
  const float* a = A + b * H;
  float s = 0.f;
  #pragma unroll
  for (int i = 0; i < 12; ++i) {
    int k = lane + 64 * i;
    s = fmaf(a[k], W[(size_t)k * H + n], s);
  }
  #pragma unroll
  for (int off = 32; off; off >>= 1) s += __shfl_xor(s, off);
  if (lane == 0) {
    if (bias) s += bias[n];
    if (act) s = tanhf(s);
    O[gid] = s;
  }
}

// ======================= bf16 MFMA GEMM =======================
// C(T x 768|1536) = act( A1 @ W1t^T [+ A2 @ W2t^T] + bias + perbatch )
// Dual-N mode: grid.x==24, cols>=768 go to Cb2/Cf2 with bias2 (col-768).
__global__ __launch_bounds__(256) void bgemm_k(
    const u16* __restrict__ A1, const u16* __restrict__ W1, int ldw1,
    const u16* __restrict__ A2, const u16* __restrict__ W2, int ldw2,
    const float* __restrict__ bias, const float* __restrict__ bias2,
    const float* __restrict__ perbatch,
    u16* __restrict__ Cb, u16* __restrict__ Cb2,
    float* __restrict__ Cf, float* __restrict__ Cf2, int act)
{
  __shared__ u16 sA[64 * 64];
  __shared__ u16 sB[64 * 64];
  int t = threadIdx.x;
  int n0 = blockIdx.x * 64;
  int m0 = blockIdx.y * 64;
  int w = t >> 6, l = t & 63, lr = l & 15, lg = l >> 4;
  int wr = (w >> 1) * 32, wc = (w & 1) * 32;

  // second-half-of-N redirect (dual-output mode)
  if (n0 >= H) { Cb = Cb2; Cf = Cf2; bias = bias2; }
  int ncol0 = (n0 >= H) ? n0 - H : n0;

  f32x4 acc[2][2];
  #pragma unroll
  for (int i = 0; i < 2; ++i)
    #pragma unroll
    for (int j = 0; j < 2; ++j) acc[i][j] = (f32x4){0.f, 0.f, 0.f, 0.f};

  int id0 = t, id1 = t + 256;
  int r0 = id0 >> 3, c0 = id0 & 7;
  int r1 = id1 >> 3, c1 = id1 & 7;

  for (int pass = 0; pass < 2; ++pass) {
    const u16* A = pass ? A2 : A1;
    const u16* W = pass ? W2 : W1;
    int ldw = pass ? ldw2 : ldw1;
    if (A == nullptr) break;
    for (int k0 = 0; k0 < H; k0 += 64) {
      uint4 a0 = *(const uint4*)(A + ((size_t)(m0 + r0)) * H + k0 + 8 * c0);
      uint4 a1 = *(const uint4*)(A + ((size_t)(m0 + r1)) * H + k0 + 8 * c1);
      uint4 b0 = *(const uint4*)(W + ((size_t)(n0 + r0)) * ldw + k0 + 8 * c0);
      uint4 b1 = *(const uint4*)(W + ((size_t)(n0 + r1)) * ldw + k0 + 8 * c1);
      if (k0 || pass) __syncthreads();
      *(uint4*)(sA + r0 * 64 + 8 * (c0 ^ (r0 & 7))) = a0;
      *(uint4*)(sA + r1 * 64 + 8 * (c1 ^ (r1 & 7))) = a1;
      *(uint4*)(sB + r0 * 64 + 8 * (c0 ^ (r0 & 7))) = b0;
      *(uint4*)(sB + r1 * 64 + 8 * (c1 ^ (r1 & 7))) = b1;
      __syncthreads();
      #pragma unroll
      for (int kh = 0; kh < 2; ++kh) {
        short8 af[2], bf[2];
        #pragma unroll
        for (int mi = 0; mi < 2; ++mi) {
          int row = wr + 16 * mi + lr;
          af[mi] = *(const short8*)(sA + row * 64 + 8 * ((4 * kh + lg) ^ (row & 7)));
        }
        #pragma unroll
        for (int ni = 0; ni < 2; ++ni) {
          int row = wc + 16 * ni + lr;
          bf[ni] = *(const short8*)(sB + row * 64 + 8 * ((4 * kh + lg) ^ (row & 7)));
        }
        #pragma unroll
        for (int mi = 0; mi < 2; ++mi)
          #pragma unroll
          for (int ni = 0; ni < 2; ++ni)
            acc[mi][ni] = __builtin_amdgcn_mfma_f32_16x16x32_bf16(af[mi], bf[ni], acc[mi][ni], 0, 0, 0);
      }
    }
  }

  #pragma unroll
  for (int mi = 0; mi < 2; ++mi) {
    #pragma unroll
    for (int reg = 0; reg < 4; ++reg) {
      int row = m0 + wr + 16 * mi + lg * 4 + reg;
      int bb = row >> 10;
      #pragma unroll
      for (int ni = 0; ni < 2; ++ni) {
        int col = ncol0 + wc + 16 * ni + lr;
        float v = acc[mi][ni][reg];
        if (bias) v += bias[col];
        if (perbatch) v += perbatch[bb * H + col];
        if (act) v = tanhf(v);
        if (Cb) Cb[(size_t)row * H + col] = f2b(v);
        if (Cf) Cf[(size_t)row * H + col] = v;
      }
    }
  }
}

// ======================= head transpose: V[T][768] -> VT[B*12][64][1024] ===========
__global__ __launch_bounds__(256) void headT_k(const u16* __restrict__ V, u16* __restrict__ VT) {
  __shared__ u16 sT[64][72];
  int t = threadIdx.x;
  int blk = blockIdx.x;
  int b = blk / 192; int rem = blk % 192; int h = rem / 16; int s0 = (rem % 16) * 64;
  int r = t >> 2, c = (t & 3) * 16;
  const uint4* src = (const uint4*)(V + ((size_t)(b * 1024 + s0 + r)) * H + h * 64 + c);
  uint4 v0 = src[0], v1 = src[1];
  *(uint4*)&sT[r][c] = v0;
  *(uint4*)&sT[r][c + 8] = v1;
  __syncthreads();
  int d = t >> 2, sc = (t & 3) * 16;
  u16 tmp[16];
  #pragma unroll
  for (int j = 0; j < 16; ++j) tmp[j] = sT[sc + j][d];
  uint4* dst = (uint4*)(VT + ((size_t)((b * 12 + h) * 64 + d)) * 1024 + s0 + sc);
  dst[0] = *(uint4*)&tmp[0];
  dst[1] = *(uint4*)&tmp[8];
}

// ======================= MFMA flash attention =======================
__global__ __launch_bounds__(256) void mattn_k(
    const u16* __restrict__ Q, const u16* __restrict__ Kg,
    const u16* __restrict__ VT, u16* __restrict__ O)
{
  __shared__ u16 sQ[64 * 64];
  __shared__ u16 sK[64 * 64];
  __shared__ u16 sV[64 * 64];
  __shared__ u16 sP[4 * 16 * 64];
  int t = threadIdx.x;
  int w = t >> 6, l = t & 63, lr = l & 15, lg = l >> 4;
  int blk = blockIdx.x;
  int b = blk / 192; int rem = blk % 192; int h = rem / 16; int q0 = (rem % 16) * 64;

  #pragma unroll
  for (int i = 0; i < 2; ++i) {
    int id = t + i * 256; int r = id >> 3, c = id & 7;
    uint4 v = *(const uint4*)(Q + ((size_t)(b * 1024 + q0 + r)) * H + h * 64 + 8 * c);
    *(uint4*)(sQ + r * 64 + 8 * (c ^ (r & 7))) = v;
  }

  f32x4 oacc[4];
  #pragma unroll
  for (int i = 0; i < 4; ++i) oacc[i] = (f32x4){0.f, 0.f, 0.f, 0.f};
  float mrow[4], lrow[4];
  #pragma unroll
  for (int i = 0; i < 4; ++i) { mrow[i] = -1e30f; lrow[i] = 0.f; }
  __syncthreads();

  for (int kt = 0; kt < 16; ++kt) {
    int kv0 = kt * 64;
    #pragma unroll
    for (int i = 0; i < 2; ++i) {
      int id = t + i * 256; int r = id >> 3, c = id & 7;
      uint4 kv = *(const uint4*)(Kg + ((size_t)(b * 1024 + kv0 + r)) * H + h * 64 + 8 * c);
      uint4 vv = *(const uint4*)(VT + ((size_t)((b * 12 + h) * 64 + r)) * 1024 + kv0 + 8 * c);
      *(uint4*)(sK + r * 64 + 8 * (c ^ (r & 7))) = kv;
      *(uint4*)(sV + r * 64 + 8 * (c ^ (r & 7))) = vv;
    }
    __syncthreads();

    f32x4 sacc[4];
    #pragma unroll
    for (int i = 0; i < 4; ++i) sacc[i] = (f32x4){0.f, 0.f, 0.f, 0.f};
    #pragma unroll
    for (int kh = 0; kh < 2; ++kh) {
      int qrow = 16 * w + lr;
      short8 qf = *(const short8*)(sQ + qrow * 64 + 8 * ((4 * kh + lg) ^ (qrow & 7)));
      #pragma unroll
      for (int ns = 0; ns < 4; ++ns) {
        int krow = 16 * ns + lr;
        short8 kf = *(const short8*)(sK + krow * 64 + 8 * ((4 * kh + lg) ^ (krow & 7)));
        sacc[ns] = __builtin_amdgcn_mfma_f32_16x16x32_bf16(qf, kf, sacc[ns], 0, 0, 0);
      }
    }

    #pragma unroll
    for (int r = 0; r < 4; ++r) {
      float mx = fmaxf(fmaxf(sacc[0][r], sacc[1][r]), fmaxf(sacc[2][r], sacc[3][r]));
      mx *= 0.125f;
      #pragma unroll
      for (int off = 1; off < 16; off <<= 1) mx = fmaxf(mx, __shfl_xor(mx, off));
      float mnew = fmaxf(mrow[r], mx);
      float resc = __expf(mrow[r] - mnew);
      mrow[r] = mnew;
      float psum = 0.f;
      int q = lg * 4 + r;
      #pragma unroll
      for (int ns = 0; ns < 4; ++ns) {
        float p = __expf(sacc[ns][r] * 0.125f - mnew);
        psum += p;
        int kv = 16 * ns + lr;
        unsigned byteoff = (unsigned)(w * 2048 + q * 128 + ((kv * 2) ^ ((q & 7) << 4)));
        *(u16*)((char*)sP + byteoff) = f2b(p);
      }
      #pragma unroll
      for (int off = 1; off < 16; off <<= 1) psum += __shfl_xor(psum, off);
      lrow[r] = lrow[r] * resc + psum;
      oacc[0][r] *= resc; oacc[1][r] *= resc; oacc[2][r] *= resc; oacc[3][r] *= resc;
    }

    #pragma unroll
    for (int kh = 0; kh < 2; ++kh) {
      short8 pf = *(const short8*)((char*)sP + w * 2048 + lr * 128 + (((4 * kh + lg) << 4) ^ ((lr & 7) << 4)));
      #pragma unroll
      for (int ds = 0; ds < 4; ++ds) {
        int vrow = 16 * ds + lr;
        short8 vf = *(const short8*)(sV + vrow * 64 + 8 * ((4 * kh + lg) ^ (vrow & 7)));
        oacc[ds] = __builtin_amdgcn_mfma_f32_16x16x32_bf16(pf, vf, oacc[ds], 0, 0, 0);
      }
    }
    __syncthreads();
  }

  #pragma unroll
  for (int r = 0; r < 4; ++r) {
    float inv = 1.0f / lrow[r];
    int qrow = q0 + 16 * w + lg * 4 + r;
    #pragma unroll
    for (int ds = 0; ds < 4; ++ds) {
      int d = 16 * ds + lr;
      O[((size_t)(b * 1024 + qrow)) * H + h * 64 + d] = f2b(oacc[ds][r] * inv);
    }
  }
}

// ======================= softmax over sequence axis (bf16 io) =======================
__global__ __launch_bounds__(256) void colsm_k(
    const u16* __restrict__ Z, const float* __restrict__ mulvec,
    const u16* __restrict__ mulmat, u16* __restrict__ O)
{
  __shared__ float red[256];
  int b = blockIdx.x / H;
  int c = blockIdx.x % H;
  int t = threadIdx.x;
  const u16* zp = Z + (size_t)b * S * H + c;
  float vals[4];
  float m = -1e30f;
  #pragma unroll
  for (int i = 0; i < 4; ++i) {
    vals[i] = b2f(zp[(size_t)(t + i * 256) * H]);
    m = fmaxf(m, vals[i]);
  }
  red[t] = m; __syncthreads();
  for (int st = 128; st; st >>= 1) { if (t < st) red[t] = fmaxf(red[t], red[t + st]); __syncthreads(); }
  m = red[0]; __syncthreads();
  float s = 0.f;
  #pragma unroll
  for (int i = 0; i < 4; ++i) { vals[i] = __expf(vals[i] - m); s += vals[i]; }
  red[t] = s; __syncthreads();
  for (int st = 128; st; st >>= 1) { if (t < st) red[t] += red[t + st]; __syncthreads(); }
  float inv = 1.0f / red[0];
  u16* op = O + (size_t)b * S * H + c;
  #pragma unroll
  for (int i = 0; i < 4; ++i) {
    int srowi = t + i * 256;
    float mult = mulvec ? mulvec[b * H + c] : b2f(mulmat[(size_t)(b * S + srowi) * H + c]);
    op[(size_t)srowi * H] = f2b(mult * vals[i] * inv);
  }
}

// ======================= gate + fusion (bf16 io) =======================
__global__ __launch_bounds__(256) void gatefuse_k(
    const u16* __restrict__ DF, const u16* __restrict__ VF,
    const float* __restrict__ GW, u16* __restrict__ FU)
{
  __shared__ float red[256];
  int tok = blockIdx.x;
  int t = threadIdx.x;
  const u16* df = DF + (size_t)tok * H;
  const u16* vf = VF + (size_t)tok * H;
  float dv[3], vv[3];
  float p = 0.f;
  #pragma unroll
  for (int i = 0; i < 3; ++i) {
    int c = t + i * 256;
    dv[i] = b2f(df[c]); vv[i] = b2f(vf[c]);
    p = fmaf(dv[i], GW[c], p);
    p = fmaf(vv[i], GW[H + c], p);
  }
  red[t] = p; __syncthreads();
  for (int st = 128; st; st >>= 1) { if (t < st) red[t] += red[t + st]; __syncthreads(); }
  float g = 1.0f / (1.0f + __expf(-red[0]));
  u16* fu = FU + (size_t)tok * H;
  #pragma unroll
  for (int i = 0; i < 3; ++i) {
    int c = t + i * 256;
    fu[c] = f2b(g * vv[i] + (1.0f - g) * dv[i]);
  }
}

// ======================= nf + final output =======================
__global__ __launch_bounds__(256) void nffinal_k(
    const u16* __restrict__ VAN, const float* __restrict__ NP,
    const float* __restrict__ NW, const float* __restrict__ FP,
    float* __restrict__ OUT)
{
  __shared__ float red[256];
  int tok = blockIdx.x;
  int t = threadIdx.x;
  const u16* va = VAN + (size_t)tok * H;
  const float* np = NP + (size_t)tok * H;
  float p = 0.f;
  #pragma unroll
  for (int i = 0; i < 3; ++i) {
    int c = t + i * 256;
    p = fmaf(b2f(va[c]), NW[c], p);
    p = fmaf(np[c], NW[H + c], p);
  }
  red[t] = p; __syncthreads();
  for (int st = 128; st; st >>= 1) { if (t < st) red[t] += red[t + st]; __syncthreads(); }
  float nf = 1.0f / (1.0f + __expf(-red[0]));
  const float* fp = FP + (size_t)tok * H;
  float* o = OUT + (size_t)tok * H;
  #pragma unroll
  for (int i = 0; i < 3; ++i) {
    int c = t + i * 256;
    o[c] = nf * tanhf(fp[c]);
  }
}

// ======================= launch =======================
extern "C" void kernel_launch(void* const* d_in, const int* in_sizes, int n_in,
                              void* d_out, int out_size, void* d_ws, size_t ws_size,
                              hipStream_t stream) {
  const float* x        = (const float*)d_in[0];
  const float* y        = (const float*)d_in[1];
  const float* vq_w     = (const float*)d_in[2];
  const float* vq_b     = (const float*)d_in[3];
  const float* vk_w     = (const float*)d_in[4];
  const float* vk_b     = (const float*)d_in[5];
  const float* vv_w     = (const float*)d_in[6];
  const float* vv_b     = (const float*)d_in[7];
  // d_in[8..11] unused (uniform softmax); d_theta_b/v_gamma_b-style constants cancel in axis-1 softmax
  const float* dv_w     = (const float*)d_in[12];
  const float* dv_b     = (const float*)d_in[13];
  const float* van_fc_w = (const float*)d_in[14];
  const float* van_fc_b = (const float*)d_in[15];
  const float* d_theta_w= (const float*)d_in[17];
  const float* WV_w     = (const float*)d_in[19];
  const float* diff_fc_w= (const float*)d_in[20];
  const float* diff_fc_b= (const float*)d_in[21];
  const float* v_gamma_w= (const float*)d_in[22];
  const float* diff_out_w=(const float*)d_in[24];
  const float* diff_out_b=(const float*)d_in[25];
  const float* van_out_w= (const float*)d_in[26];
  const float* van_out_b= (const float*)d_in[27];
  const float* diff_fus_w=(const float*)d_in[28];
  const float* diff_fus_b=(const float*)d_in[29];
  const float* van_fus_w= (const float*)d_in[30];
  const float* van_fus_b= (const float*)d_in[31];
  const float* gate_w   = (const float*)d_in[32];
  const float* nf_w     = (const float*)d_in[33];
  const float* nf_b     = (const float*)d_in[34];
  const float* nf_out_w = (const float*)d_in[35];
  const float* final_w  = (const float*)d_in[36];
  const float* final_b  = (const float*)d_in[37];
  float* out = (float*)d_out;

  // ---- workspace layout ----
  u16* wt = (u16*)d_ws;
  const size_t HH_ = (size_t)H * H;
  const size_t HH2 = 2 * HH_;
  // order matters: (vk,vv), (vanfc,WV), (nf,final) must be adjacent for dual-N merges
  size_t woff[14];
  const float* wsrc[14] = {vq_w, vk_w, vv_w, van_fc_w, WV_w, diff_fc_w, diff_fus_w, van_fus_w,
                           nf_w, final_w, d_theta_w, v_gamma_w, diff_out_w, van_out_w};
  int wk[14] = {12,12,12,12,12,12,12,12,12,12, 24,24,24,24};
  size_t o = 0;
  for (int i = 0; i < 14; ++i) { woff[i] = o; o += (i < 10) ? HH_ : HH2; }
  u16* bufs = wt + o;
  u16* bX   = bufs + 0 * TH;
  u16* bY   = bufs + 1 * TH;
  u16* bQ   = bufs + 2 * TH;
  u16* bK   = bufs + 3 * TH;
  u16* bV   = bufs + 4 * TH;
  u16* bVT  = bufs + 5 * TH;
  u16* bVan = bufs + 6 * TH;
  float* F0 = (float*)(bufs + 7 * TH);  // nf_pre
  float* F1 = F0 + TH;                  // final_pre
  float* sm = F1 + TH;
  float* ybar  = sm;            // 1536
  float* dvbar = sm + 1536;     // 1536
  float* c2    = sm + 3072;     // 1536
  float* part  = sm + 4608;     // 16 x 768 partials

  // ---- weight prep + input conversion ----
  WprepArgs wa;
  int ts = 0;
  for (int i = 0; i < 14; ++i) {
    wa.src[i] = wsrc[i];
    wa.dst[i] = (unsigned)woff[i];
    wa.ktiles[i] = wk[i];
    wa.tstart[i] = ts;
    ts += wk[i] * 12;
  }
  wa.tstart[14] = ts;
  wprep_k<<<ts, 256, 0, stream>>>(wa, wt);
  cvt_k<<<TH / 8 / 256, 256, 0, stream>>>(x, bX);
  cvt_k<<<TH / 8 / 256, 256, 0, stream>>>(y, bY);

  // ---- differential path constants (parallelized; c1/wd deleted — cancel in axis-1 softmax) ----
  meany1_k<<<48, 256, 0, stream>>>(y, part);
  meany2_k<<<6, 256, 0, stream>>>(part, ybar);
  gemv_k<<<384, 256, 0, stream>>>(ybar, dv_w, dv_b, dvbar, 0);          // diff_vector[b,:]
  gemv_k<<<384, 256, 0, stream>>>(dvbar, diff_out_w, diff_out_b, c2, 0); // top-half diff_out contribution

  dim3 gg(12, 32), gg2(24, 32);
  const u16 *wt_vq = wt + woff[0], *wt_vk = wt + woff[1],
            *wt_vanfc = wt + woff[3], *wt_difffc = wt + woff[5],
            *wt_difffus = wt + woff[6], *wt_vanfus = wt + woff[7], *wt_nf = wt + woff[8],
            *wt_dtheta = wt + woff[10], *wt_vg = wt + woff[11],
            *wt_diffout = wt + woff[12], *wt_vanout = wt + woff[13];
  #define NO nullptr

  // Q = x@vq + b -> bQ
  bgemm_k<<<gg, 256, 0, stream>>>(bX, wt_vq, H, NO, NO, 0, vq_b, NO, NO, bQ, NO, NO, NO, 0);
  // K,V merged (wt_vk,wt_vv adjacent): K->bK, V->bV
  bgemm_k<<<gg2, 256, 0, stream>>>(bY, wt_vk, H, NO, NO, 0, vk_b, vv_b, NO, bK, bV, NO, NO, 0);
  headT_k<<<384, 256, 0, stream>>>(bV, bVT);
  mattn_k<<<384, 256, 0, stream>>>(bQ, bK, bVT, bVan);

  // tv,gA merged (wt_vanfc,wt_WV adjacent): tv->bX, gA->bK
  bgemm_k<<<gg2, 256, 0, stream>>>(bVan, wt_vanfc, H, NO, NO, 0, van_fc_b, NO, NO, bX, bK, NO, NO, 1);
  // z1 = tv@dth[H:2H] (bias cancels in axis-1 softmax) -> bY
  bgemm_k<<<gg, 256, 0, stream>>>(bX, wt_dtheta + H, 2 * H, NO, NO, 0, NO, NO, NO, bY, NO, NO, NO, 0);
  // d_theta = dvbar * softmax_axis1(z1) -> bQ
  colsm_k<<<BATCH * H, 256, 0, stream>>>(bY, dvbar, NO, bQ);
  // gB = tanh(d_theta@diff_fc + b) -> bV
  bgemm_k<<<gg, 256, 0, stream>>>(bQ, wt_difffc, H, NO, NO, 0, diff_fc_b, NO, NO, bV, NO, NO, NO, 1);
  // z2 = gA@vg1 + gB@vg2 (v_gamma_b cancels) -> bX... wait bX holds tv (dead after z1) -> ok? tv used only for z1. yes.
  bgemm_k<<<gg, 256, 0, stream>>>(bK, wt_vg, 2 * H, bV, wt_vg + H, 2 * H, NO, NO, NO, bX, NO, NO, NO, 0);
  // a_gamma = van * softmax_axis1(z2) -> bX in place
  colsm_k<<<BATCH * H, 256, 0, stream>>>(bX, NO, bVan, bX);
  // diff_out = tanh(d_theta@diffout[H:2H] + c2) -> bY
  bgemm_k<<<gg, 256, 0, stream>>>(bQ, wt_diffout + H, 2 * H, NO, NO, 0, NO, NO, c2, bY, NO, NO, NO, 1);
  // van_out = tanh(van@vanout1 + a_gamma@vanout2 + b) -> bK
  bgemm_k<<<gg, 256, 0, stream>>>(bVan, wt_vanout, 2 * H, bX, wt_vanout + H, 2 * H, van_out_b, NO, NO, bK, NO, NO, NO, 1);
  // diff_fusion = tanh(diff_out@diff_fus + b) -> bQ
  bgemm_k<<<gg, 256, 0, stream>>>(bY, wt_difffus, H, NO, NO, 0, diff_fus_b, NO, NO, bQ, NO, NO, NO, 1);
  // van_fusion = tanh(van_out@van_fus + b) -> bX
  bgemm_k<<<gg, 256, 0, stream>>>(bK, wt_vanfus, H, NO, NO, 0, van_fus_b, NO, NO, bX, NO, NO, NO, 1);
  // fusion -> bY
  gatefuse_k<<<T, 256, 0, stream>>>(bQ, bX, gate_w, bY);
  // nf_pre,final_pre merged (wt_nf,wt_final adjacent): F0, F1 (f32)
  bgemm_k<<<gg2, 256, 0, stream>>>(bY, wt_nf, H, NO, NO, 0, nf_b, final_b, NO, NO, NO, F0, F1, 0);
  // out = sigmoid([van, nf_pre]@nf_out) * tanh(final_pre)
  nffinal_k<<<T, 256, 0, stream>>>(bVan, F0, nf_out_w, F1, out);
}